// Round 1
// 109.724 us; speedup vs baseline: 1.0122x; 1.0122x over previous
//
#include <hip/hip_runtime.h>

// WaveletLinear: y[b,o] = sum_i w[o,i] * (1 - s^2) * exp(-0.5 s^2),
//   s = (x[b,i] - t[o,i]) / (A_MIN + softplus(sr[o,i]) + EPS)
// Rework: u = K*s^2, K = 0.5*log2(e); e = exp2(-u);
//   y = sum w*e - (1/K) * sum w*(u*e)   (split accumulators E and U)
//
// R6: two fixes over R5.
//  (a) wl_prep rewritten: coalesced float4 reads (lane along i) + LDS
//      transpose + 512-block grid (R5 prep read lane=o = 64-line scatter on a
//      128-block/half-idle grid -> latency-bound, suspected ~45us of total).
//  (b) wl_main b-tile 16 -> 8: grid 1024 blocks -> 4 blocks/CU (8 waves/SIMD,
//      launch_bounds(512,8)). R5's 2 blocks/CU (4 waves/SIMD) left VALU+trans
//      pipes at 60% busy (issue floor ~31us vs 56us measured) -- the extra
//      waves cover the per-batch P3 vmcnt stalls. Inner loop body unchanged.
//      Waves split i 8-ways; two-round LDS reduction at the end.

#define WL_A_MIN 0.001f
#define WL_EPS   1e-8f

constexpr int WL_B = 512;
constexpr int WL_O = 1024;
constexpr int WL_I = 512;

// K = 0.5*log2(e); sqrt(K); 1/K; log2(e); ln(2)
#define WL_SQK  0.84932180553704583800f
#define WL_IK   1.38629436111989061883f
#define WL_L2E  1.44269504088896340736f
#define WL_LN2  0.69314718055994530942f

typedef float v2f __attribute__((ext_vector_type(2)));

struct P3 { float nti, inv, w; };          // 12 B

__device__ __forceinline__ float fast_exp2(float a) {
#if __has_builtin(__builtin_amdgcn_exp2f)
    return __builtin_amdgcn_exp2f(a);
#else
    return exp2f(a);
#endif
}
__device__ __forceinline__ float fast_log2(float a) {
#if __has_builtin(__builtin_amdgcn_logf)
    return __builtin_amdgcn_logf(a);
#else
    return __log2f(a);
#endif
}
__device__ __forceinline__ float fast_rcp(float a) {
#if __has_builtin(__builtin_amdgcn_rcpf)
    return __builtin_amdgcn_rcpf(a);
#else
    return 1.0f / a;
#endif
}

// Param precompute. Block = 256 thr handles a 64(o) x 16(i) tile.
// Phase 1: coalesced float4 reads (4 lanes cover 64B of one o-row), compute
// P3, store transposed into LDS. Phase 2: lane=o, dwordx3 writes of
// pT3[i*O+o] -> 768B/wave contiguous. Grid (16,32)=512 blocks = full GPU.
__global__ __launch_bounds__(256) void wl_prep(
    const float* __restrict__ translation,
    const float* __restrict__ scale_raw,
    const float* __restrict__ weights,
    P3* __restrict__ pT3)
{
    __shared__ P3 lds[16 * 64];                        // 12 KB  [i_l][o_l]
    const int t  = threadIdx.x;
    const int o0 = blockIdx.x * 64;
    const int i0 = blockIdx.y * 16;

    {
        const int o_l = t >> 2;                        // 0..63
        const int iq  = t & 3;                         // 0..3 -> 4 i each
        const size_t g = (size_t)(o0 + o_l) * WL_I + (i0 + iq * 4);
        const float4 tv = *reinterpret_cast<const float4*>(translation + g);
        const float4 sv = *reinterpret_cast<const float4*>(scale_raw   + g);
        const float4 wv = *reinterpret_cast<const float4*>(weights     + g);
        const float tt[4] = {tv.x, tv.y, tv.z, tv.w};
        const float ss[4] = {sv.x, sv.y, sv.z, sv.w};
        const float ww[4] = {wv.x, wv.y, wv.z, wv.w};
        #pragma unroll
        for (int j = 0; j < 4; ++j) {
            float ex  = fast_exp2(ss[j] * WL_L2E);     // softplus via hw exp2/log2
            float sp  = fast_log2(1.0f + ex) * WL_LN2;
            float inv = fast_rcp(WL_A_MIN + sp + WL_EPS) * WL_SQK;
            P3 pv; pv.nti = -tt[j] * inv; pv.inv = inv; pv.w = ww[j];
            lds[(iq * 4 + j) * 64 + o_l] = pv;
        }
    }
    __syncthreads();
    {
        const int o_l = t & 63;
        const int r   = t >> 6;                        // 0..3 -> 4 i each
        #pragma unroll
        for (int j = 0; j < 4; ++j) {
            const int i_l = r * 4 + j;
            pT3[(size_t)(i0 + i_l) * WL_O + (o0 + o_l)] = lds[i_l * 64 + o_l];
        }
    }
}

// Main: grid (O/64=16, B/8=64) = 1024 blocks (4/CU), 512 thr = 8 waves.
// Wave wid = i-eighth (64 i's); every wave covers all 8 b of the tile.
// gx-major linear ids -> each o-slab stays on one XCD's L2 (16 slabs, 8 XCDs).
__global__ __launch_bounds__(512, 8) void wl_main(
    const float* __restrict__ x,
    const P3* __restrict__ pT3,
    float* __restrict__ out)
{
    __shared__ float smem[5120];                       // 20 KB: xT (16KB) then reduce (20KB)

    const int tid  = threadIdx.x;
    const int lane = tid & 63;
    const int wid  = tid >> 6;                         // 0..7 = i-eighth
    const int o    = blockIdx.x * 64 + lane;
    const int b0   = blockIdx.y * 8;

    // ---- stage x^T once: xT[i*8 + b_l]; one wave per b-row, coalesced ----
    {
        const int b_l = tid & 7;
        const int seg = tid >> 3;                      // 0..63 -> i in [seg*8,+8)
        const float* xg = &x[(size_t)(b0 + b_l) * WL_I + seg * 8];
        const float4 v0 = *reinterpret_cast<const float4*>(xg);
        const float4 v1 = *reinterpret_cast<const float4*>(xg + 4);
        const int base = seg * 64 + b_l;
        smem[base +  0] = v0.x;
        smem[base +  8] = v0.y;
        smem[base + 16] = v0.z;
        smem[base + 24] = v0.w;
        smem[base + 32] = v1.x;
        smem[base + 40] = v1.y;
        smem[base + 48] = v1.z;
        smem[base + 56] = v1.w;
    }
    __syncthreads();

    const P3*    pp = pT3 + (size_t)(wid * 64) * WL_O + o;   // 768B/wave coalesced
    const float* xr = &smem[wid * 64 * 8];                   // uniform per wave

    v2f aE0 = {0.f,0.f}, aE1 = {0.f,0.f}, aE2 = {0.f,0.f}, aE3 = {0.f,0.f};
    v2f aU0 = {0.f,0.f}, aU1 = {0.f,0.f}, aU2 = {0.f,0.f}, aU3 = {0.f,0.f};

    #pragma unroll 4
    for (int ii = 0; ii < 64; ++ii) {
        const P3 p = *pp;  pp += WL_O;
        const float4 xa = *reinterpret_cast<const float4*>(xr);      // b 0..3 (broadcast)
        const float4 xb = *reinterpret_cast<const float4*>(xr + 4);  // b 4..7 (broadcast)
        xr += 8;

        v2f nti = {p.nti, p.nti};
        v2f inv = {p.inv, p.inv};
        v2f wv  = {p.w,  p.w};

        v2f x01 = {xa.x, xa.y};
        v2f x23 = {xa.z, xa.w};
        v2f x45 = {xb.x, xb.y};
        v2f x67 = {xb.z, xb.w};

        v2f s0 = __builtin_elementwise_fma(x01, inv, nti);
        v2f s1 = __builtin_elementwise_fma(x23, inv, nti);
        v2f s2 = __builtin_elementwise_fma(x45, inv, nti);
        v2f s3 = __builtin_elementwise_fma(x67, inv, nti);
        v2f u0 = s0 * s0;
        v2f u1 = s1 * s1;
        v2f u2 = s2 * s2;
        v2f u3 = s3 * s3;
        v2f e0 = {fast_exp2(-u0.x), fast_exp2(-u0.y)};
        v2f e1 = {fast_exp2(-u1.x), fast_exp2(-u1.y)};
        v2f e2 = {fast_exp2(-u2.x), fast_exp2(-u2.y)};
        v2f e3 = {fast_exp2(-u3.x), fast_exp2(-u3.y)};
        aE0 = __builtin_elementwise_fma(wv, e0, aE0);
        aE1 = __builtin_elementwise_fma(wv, e1, aE1);
        aE2 = __builtin_elementwise_fma(wv, e2, aE2);
        aE3 = __builtin_elementwise_fma(wv, e3, aE3);
        v2f ue0 = u0 * e0;
        v2f ue1 = u1 * e1;
        v2f ue2 = u2 * e2;
        v2f ue3 = u3 * e3;
        aU0 = __builtin_elementwise_fma(wv, ue0, aU0);
        aU1 = __builtin_elementwise_fma(wv, ue1, aU1);
        aU2 = __builtin_elementwise_fma(wv, ue2, aU2);
        aU3 = __builtin_elementwise_fma(wv, ue3, aU3);
    }

    // ---- two-round 8-way reduce over i-eighths ----
    __syncthreads();                                   // done reading xT
    constexpr int RS = 20;                             // row stride (floats), bank-spread, 80B (16B-aligned)
    if (wid >= 4) {                                    // round 1: waves 4..7 dump
        float4* dst = reinterpret_cast<float4*>(&smem[((wid - 4) * 64 + lane) * RS]);
        dst[0] = make_float4(aE0.x, aE0.y, aE1.x, aE1.y);
        dst[1] = make_float4(aE2.x, aE2.y, aE3.x, aE3.y);
        dst[2] = make_float4(aU0.x, aU0.y, aU1.x, aU1.y);
        dst[3] = make_float4(aU2.x, aU2.y, aU3.x, aU3.y);
    }
    __syncthreads();
    if (wid < 4) {                                     // waves 0..3 absorb 4..7
        const float4* src = reinterpret_cast<const float4*>(&smem[(wid * 64 + lane) * RS]);
        const float4 v0 = src[0], v1 = src[1], v2 = src[2], v3 = src[3];
        aE0.x += v0.x; aE0.y += v0.y; aE1.x += v0.z; aE1.y += v0.w;
        aE2.x += v1.x; aE2.y += v1.y; aE3.x += v1.z; aE3.y += v1.w;
        aU0.x += v2.x; aU0.y += v2.y; aU1.x += v2.z; aU1.y += v2.w;
        aU2.x += v3.x; aU2.y += v3.y; aU3.x += v3.z; aU3.y += v3.w;
    }
    __syncthreads();
    if (wid >= 1 && wid < 4) {                         // round 2: waves 1..3 dump
        float4* dst = reinterpret_cast<float4*>(&smem[((wid - 1) * 64 + lane) * RS]);
        dst[0] = make_float4(aE0.x, aE0.y, aE1.x, aE1.y);
        dst[1] = make_float4(aE2.x, aE2.y, aE3.x, aE3.y);
        dst[2] = make_float4(aU0.x, aU0.y, aU1.x, aU1.y);
        dst[3] = make_float4(aU2.x, aU2.y, aU3.x, aU3.y);
    }
    __syncthreads();
    if (wid == 0) {                                    // wave 0 combines + stores
        float E[8] = {aE0.x, aE0.y, aE1.x, aE1.y, aE2.x, aE2.y, aE3.x, aE3.y};
        float U[8] = {aU0.x, aU0.y, aU1.x, aU1.y, aU2.x, aU2.y, aU3.x, aU3.y};
        #pragma unroll
        for (int q = 0; q < 3; ++q) {
            const float4* src = reinterpret_cast<const float4*>(&smem[(q * 64 + lane) * RS]);
            const float4 v0 = src[0], v1 = src[1], v2 = src[2], v3 = src[3];
            E[0] += v0.x; E[1] += v0.y; E[2] += v0.z; E[3] += v0.w;
            E[4] += v1.x; E[5] += v1.y; E[6] += v1.z; E[7] += v1.w;
            U[0] += v2.x; U[1] += v2.y; U[2] += v2.z; U[3] += v2.w;
            U[4] += v3.x; U[5] += v3.y; U[6] += v3.z; U[7] += v3.w;
        }
        #pragma unroll
        for (int k = 0; k < 8; ++k)
            out[(size_t)(b0 + k) * WL_O + o] = fmaf(-WL_IK, U[k], E[k]);
    }
}

extern "C" void kernel_launch(void* const* d_in, const int* in_sizes, int n_in,
                              void* d_out, int out_size, void* d_ws, size_t ws_size,
                              hipStream_t stream) {
    const float* x           = (const float*)d_in[0];
    const float* translation = (const float*)d_in[1];
    const float* scale_raw   = (const float*)d_in[2];
    const float* weights     = (const float*)d_in[3];
    float*       out         = (float*)d_out;
    P3*          pT3         = (P3*)d_ws;              // 6.3 MB (<= 8 MB, R1-proven)

    wl_prep<<<dim3(WL_O / 64, WL_I / 16), dim3(256), 0, stream>>>(
        translation, scale_raw, weights, pT3);

    wl_main<<<dim3(WL_O / 64, WL_B / 8), dim3(512), 0, stream>>>(
        x, pT3, out);
}